// Round 2
// baseline (169.931 us; speedup 1.0000x reference)
//
#include <hip/hip_runtime.h>
#include <hip/hip_bf16.h>

typedef unsigned short u16;
typedef __attribute__((ext_vector_type(8))) __bf16 bf16x8;
typedef __attribute__((ext_vector_type(4))) float f32x4;

#define B_ 4
#define T_ 2048
#define C_ 1024
#define H_ 64
#define PITCH 72  // bf16 elems per LDS row (144 B) — breaks pow2 bank stride

__device__ __forceinline__ u16 f2bf(float f) {
    union { __hip_bfloat16 h; u16 u; } cv;
    cv.h = __float2bfloat16(f);
    return cv.u;
}

// load 8 consecutive floats, convert to bf16, store 16B to LDS
__device__ __forceinline__ void cvt8(const float* __restrict__ src, u16* dst) {
    float4 f0 = *(const float4*)(src);
    float4 f1 = *(const float4*)(src + 4);
    union { u16 h[8]; uint4 u; } r;
    r.h[0] = f2bf(f0.x); r.h[1] = f2bf(f0.y); r.h[2] = f2bf(f0.z); r.h[3] = f2bf(f0.w);
    r.h[4] = f2bf(f1.x); r.h[5] = f2bf(f1.y); r.h[6] = f2bf(f1.z); r.h[7] = f2bf(f1.w);
    *(uint4*)dst = r.u;
}

// ---------------- Kernel 1: QKV projection ----------------
// out[m][n] = sum_k x[m][k] * W[n][k]; W rows 0-63=Wq, 64-127=Wk, 128-191=Wv
// Block: 32 rows (M) x 192 cols (N). 4 waves: wave w -> M-strip (w&1), N-half (w>>1).
__global__ __launch_bounds__(256) void qkv_proj(
    const float* __restrict__ x, const float* __restrict__ wq,
    const float* __restrict__ wk, const float* __restrict__ wv,
    u16* __restrict__ q, u16* __restrict__ k, u16* __restrict__ v)
{
    __shared__ u16 xs[32 * PITCH];
    __shared__ u16 ws[192 * PITCH];

    const int tid  = threadIdx.x;
    const int lane = tid & 63;
    const int w    = tid >> 6;
    const int mstrip = (w & 1) * 16;
    const int nhalf  = (w >> 1) * 96;
    const int m0   = blockIdx.x * 32;

    const int lr = lane & 15;        // fragment row/col
    const int g  = lane >> 4;        // 0..3
    const int lk = g * 8;            // k offset within 32

    const int srow = tid >> 3;       // 0..31
    const int scol = (tid & 7) * 8;  // 0..56 step 8

    f32x4 acc[6] = {};

    for (int k0 = 0; k0 < C_; k0 += 64) {
        __syncthreads();
        // stage x tile: 32 rows x 64 cols (fp32 -> bf16)
        cvt8(x + (size_t)(m0 + srow) * C_ + k0 + scol, xs + srow * PITCH + scol);
        // stage W tile: 192 rows x 64 cols
        #pragma unroll
        for (int gg = 0; gg < 6; ++gg) {
            int r = gg * 32 + srow;
            const float* src = (gg < 2) ? (wq + (size_t)r * C_)
                             : (gg < 4) ? (wk + (size_t)(r - 64) * C_)
                                        : (wv + (size_t)(r - 128) * C_);
            cvt8(src + k0 + scol, ws + r * PITCH + scol);
        }
        __syncthreads();

        #pragma unroll
        for (int ks = 0; ks < 2; ++ks) {
            bf16x8 a = *(const bf16x8*)(xs + (mstrip + lr) * PITCH + ks * 32 + lk);
            #pragma unroll
            for (int j = 0; j < 6; ++j) {
                bf16x8 b = *(const bf16x8*)(ws + (nhalf + j * 16 + lr) * PITCH + ks * 32 + lk);
                acc[j] = __builtin_amdgcn_mfma_f32_16x16x32_bf16(a, b, acc[j], 0, 0, 0);
            }
        }
    }

    // epilogue: C/D layout col=lane&15, row=(lane>>4)*4+i
    #pragma unroll
    for (int j = 0; j < 6; ++j) {
        int n = nhalf + j * 16 + lr;
        u16* dst; int h;
        if (n < 64)       { dst = q; h = n; }
        else if (n < 128) { dst = k; h = n - 64; }
        else              { dst = v; h = n - 128; }
        #pragma unroll
        for (int i = 0; i < 4; ++i) {
            int m = m0 + mstrip + g * 4 + i;
            dst[(size_t)m * H_ + h] = f2bf(acc[j][i]);
        }
    }
}

// ---------------- Kernel 2: causal flash attention ----------------
// Block = (batch, 32-row q-tile), 2 waves x 16 rows. KV chunks of 64.
__global__ __launch_bounds__(128) void attn(
    const u16* __restrict__ q, const u16* __restrict__ k,
    const u16* __restrict__ v, float* __restrict__ out)
{
    __shared__ u16 ks_[64 * PITCH];
    __shared__ u16 vs[64 * PITCH];   // transposed: vs[d][kv]
    __shared__ u16 ps[2 * 16 * PITCH];

    const int tid  = threadIdx.x;
    const int lane = tid & 63;
    const int w    = tid >> 6;       // 0..1
    const int b    = blockIdx.x >> 6;
    const int qt   = blockIdx.x & 63;
    const int q0   = qt * 32;
    const size_t bT = (size_t)b * T_;

    const int lr = lane & 15;
    const int g  = lane >> 4;
    const int lk = g * 8;

    const int srow4 = tid >> 3;       // 0..15
    const int scol  = (tid & 7) * 8;

    // Q fragments (A layout): row = lr, k = ks*32 + lk + j
    bf16x8 aq[2];
    #pragma unroll
    for (int ks2 = 0; ks2 < 2; ++ks2)
        aq[ks2] = *(const bf16x8*)(q + (bT + q0 + w * 16 + lr) * H_ + ks2 * 32 + lk);

    f32x4 oacc[4] = {};
    float mrow[4], lrow[4];
    #pragma unroll
    for (int i = 0; i < 4; ++i) { mrow[i] = -1e30f; lrow[i] = 0.f; }

    const int jmax = (q0 + 31) >> 6;

    for (int jc = 0; jc <= jmax; ++jc) {
        const int kv0 = jc * 64;
        __syncthreads();
        // stage K: rows kv0+r (64 x 64)
        #pragma unroll
        for (int gg = 0; gg < 4; ++gg) {
            int r = gg * 16 + srow4;
            uint4 d = *(const uint4*)(k + (bT + kv0 + r) * H_ + scol);
            *(uint4*)(ks_ + r * PITCH + scol) = d;
        }
        // stage V transposed: vs[d][kv]
        #pragma unroll
        for (int gg = 0; gg < 4; ++gg) {
            int r = gg * 16 + srow4;
            uint4 d = *(const uint4*)(v + (bT + kv0 + r) * H_ + scol);
            const u16* e = (const u16*)&d;
            #pragma unroll
            for (int jj = 0; jj < 8; ++jj)
                vs[(scol + jj) * PITCH + r] = e[jj];
        }
        __syncthreads();

        // S = Q K^T  (B frag from K rows: B[k][n] = K[n][k])
        f32x4 sacc[4];
        #pragma unroll
        for (int j = 0; j < 4; ++j) {
            sacc[j] = f32x4{0.f, 0.f, 0.f, 0.f};
            #pragma unroll
            for (int ks2 = 0; ks2 < 2; ++ks2) {
                bf16x8 bk = *(const bf16x8*)(ks_ + (j * 16 + lr) * PITCH + ks2 * 32 + lk);
                sacc[j] = __builtin_amdgcn_mfma_f32_16x16x32_bf16(aq[ks2], bk, sacc[j], 0, 0, 0);
            }
        }

        // scale + causal mask
        float s[4][4];
        #pragma unroll
        for (int j = 0; j < 4; ++j) {
            int col = kv0 + j * 16 + lr;
            #pragma unroll
            for (int i = 0; i < 4; ++i) {
                int row = q0 + w * 16 + g * 4 + i;
                float val = sacc[j][i] * 0.03125f;
                s[j][i] = (col <= row) ? val : -1e30f;
            }
        }

        // online softmax (rows live in 16-lane groups; reduce with shfl_xor 1,2,4,8)
        float pnew[4][4];
        #pragma unroll
        for (int i = 0; i < 4; ++i) {
            float mx = fmaxf(fmaxf(s[0][i], s[1][i]), fmaxf(s[2][i], s[3][i]));
            mx = fmaxf(mx, __shfl_xor(mx, 1));
            mx = fmaxf(mx, __shfl_xor(mx, 2));
            mx = fmaxf(mx, __shfl_xor(mx, 4));
            mx = fmaxf(mx, __shfl_xor(mx, 8));
            float mnew = fmaxf(mrow[i], mx);
            float corr = __expf(mrow[i] - mnew);
            float rs = 0.f;
            #pragma unroll
            for (int j = 0; j < 4; ++j) {
                float p = __expf(s[j][i] - mnew);
                pnew[j][i] = p;
                rs += p;
            }
            rs += __shfl_xor(rs, 1);
            rs += __shfl_xor(rs, 2);
            rs += __shfl_xor(rs, 4);
            rs += __shfl_xor(rs, 8);
            lrow[i] = lrow[i] * corr + rs;
            mrow[i] = mnew;
            #pragma unroll
            for (int j = 0; j < 4; ++j) oacc[j][i] *= corr;
        }

        // P -> LDS (wave-private region), then PV via MFMA
        #pragma unroll
        for (int j = 0; j < 4; ++j)
            #pragma unroll
            for (int i = 0; i < 4; ++i)
                ps[(w * 16 + g * 4 + i) * PITCH + j * 16 + lr] = f2bf(pnew[j][i]);

        #pragma unroll
        for (int ks2 = 0; ks2 < 2; ++ks2) {
            bf16x8 ap = *(const bf16x8*)(ps + (w * 16 + lr) * PITCH + ks2 * 32 + lk);
            #pragma unroll
            for (int j = 0; j < 4; ++j) {
                bf16x8 bv = *(const bf16x8*)(vs + (j * 16 + lr) * PITCH + ks2 * 32 + lk);
                oacc[j] = __builtin_amdgcn_mfma_f32_16x16x32_bf16(ap, bv, oacc[j], 0, 0, 0);
            }
        }
    }

    // epilogue: out = oacc / l  (fp32 output)
    #pragma unroll
    for (int j = 0; j < 4; ++j)
        #pragma unroll
        for (int i = 0; i < 4; ++i) {
            int row = q0 + w * 16 + g * 4 + i;
            out[(bT + row) * H_ + j * 16 + lr] = oacc[j][i] / lrow[i];
        }
}

extern "C" void kernel_launch(void* const* d_in, const int* in_sizes, int n_in,
                              void* d_out, int out_size, void* d_ws, size_t ws_size,
                              hipStream_t stream) {
    const float* x  = (const float*)d_in[0];
    const float* wq = (const float*)d_in[1];
    const float* wk = (const float*)d_in[2];
    const float* wv = (const float*)d_in[3];

    u16* qws = (u16*)d_ws;
    u16* kws = qws + (size_t)B_ * T_ * H_;
    u16* vws = kws + (size_t)B_ * T_ * H_;

    qkv_proj<<<256, 256, 0, stream>>>(x, wq, wk, wv, qws, kws, vws);
    attn<<<256, 128, 0, stream>>>(qws, kws, vws, (float*)d_out);
}

// Round 3
// 90.058 us; speedup vs baseline: 1.8869x; 1.8869x over previous
//
#include <hip/hip_runtime.h>
#include <hip/hip_bf16.h>

typedef unsigned short u16;
typedef __attribute__((ext_vector_type(8))) __bf16 bf16x8;
typedef __attribute__((ext_vector_type(4))) float f32x4;

#define B_ 4
#define T_ 2048
#define C_ 1024
#define H_ 64

__device__ __forceinline__ u16 f2bf(float f) {
    union { __hip_bfloat16 h; u16 u; } cv;
    cv.h = __float2bfloat16(f);
    return cv.u;
}

// ---------------- Kernel 0: W fp32 -> bf16 (once) ----------------
// wcat[192][1024]: rows 0-63 Wq, 64-127 Wk, 128-191 Wv
__global__ __launch_bounds__(256) void wcvt(
    const float* __restrict__ wq, const float* __restrict__ wk,
    const float* __restrict__ wv, u16* __restrict__ wcat)
{
    int e = (blockIdx.x * 256 + threadIdx.x) * 4;   // 49152 threads * 4 elems
    int row = e >> 10, col = e & 1023;
    const float* src = (row < 64) ? (wq + (size_t)row * C_)
                     : (row < 128) ? (wk + (size_t)(row - 64) * C_)
                                   : (wv + (size_t)(row - 128) * C_);
    float4 f = *(const float4*)(src + col);
    u16 o[4] = { f2bf(f.x), f2bf(f.y), f2bf(f.z), f2bf(f.w) };
    *(uint2*)(wcat + e) = *(uint2*)o;
}

// ---------------- Kernel 1: QKV projection (LDS-free) ----------------
// wave = 16 rows (M) x 96 cols (N-half). 1024 waves total.
__global__ __launch_bounds__(256) void qkv(
    const float* __restrict__ x, const u16* __restrict__ wcat,
    u16* __restrict__ q, u16* __restrict__ k, u16* __restrict__ vT)
{
    const int tid  = threadIdx.x;
    const int lane = tid & 63;
    const int gw   = blockIdx.x * 4 + (tid >> 6);
    const int mtile = gw >> 1;
    const int nhalf = (gw & 1) * 96;

    const int lr = lane & 15;
    const int g  = lane >> 4;
    const int lk = g * 8;

    const float* xrow  = x + (size_t)(mtile * 16 + lr) * C_ + lk;
    const u16*   wbase = wcat + (size_t)(nhalf + lr) * C_ + lk;

    f32x4 acc[6] = {};

    for (int k0 = 0; k0 < C_; k0 += 32) {
        float4 f0 = *(const float4*)(xrow + k0);
        float4 f1 = *(const float4*)(xrow + k0 + 4);
        union { u16 h[8]; bf16x8 v; } ua;
        ua.h[0] = f2bf(f0.x); ua.h[1] = f2bf(f0.y);
        ua.h[2] = f2bf(f0.z); ua.h[3] = f2bf(f0.w);
        ua.h[4] = f2bf(f1.x); ua.h[5] = f2bf(f1.y);
        ua.h[6] = f2bf(f1.z); ua.h[7] = f2bf(f1.w);
        #pragma unroll
        for (int j = 0; j < 6; ++j) {
            bf16x8 b = *(const bf16x8*)(wbase + (size_t)j * 16 * C_ + k0);
            acc[j] = __builtin_amdgcn_mfma_f32_16x16x32_bf16(ua.v, b, acc[j], 0, 0, 0);
        }
    }

    // epilogue: C/D layout col=lane&15, row=(lane>>4)*4+i
    const int m0 = mtile * 16;
    #pragma unroll
    for (int j = 0; j < 6; ++j) {
        int n = nhalf + j * 16 + lr;
        #pragma unroll
        for (int i = 0; i < 4; ++i) {
            int m = m0 + g * 4 + i;
            u16 val = f2bf(acc[j][i]);
            if (n < 64) {
                q[(size_t)m * H_ + n] = val;
            } else if (n < 128) {
                k[(size_t)m * H_ + (n - 64)] = val;
            } else {
                int b = m >> 11, t = m & 2047;
                vT[((size_t)b * H_ + (n - 128)) * T_ + t] = val;
            }
        }
    }
}

// ---------------- Kernel 2: causal flash attention ----------------
// 1 wave per 16-row q-tile; K/V direct from L2; only P through LDS.
__global__ __launch_bounds__(64) void attn(
    const u16* __restrict__ q, const u16* __restrict__ k,
    const u16* __restrict__ vT, float* __restrict__ out)
{
    __shared__ u16 ps[16 * 72];

    const int lane = threadIdx.x;
    const int bid  = blockIdx.x;
    const int b    = bid & 3;
    const int qt   = 127 - (bid >> 2);   // longest tiles dispatch first
    const int q0   = qt * 16;            // local row offset
    const size_t bT = (size_t)b * T_;

    const int lr = lane & 15;
    const int g  = lane >> 4;
    const int lk = g * 8;

    // Q A-fragments: row=lr, k=ks*32+lk
    bf16x8 aq[2];
    #pragma unroll
    for (int ks = 0; ks < 2; ++ks)
        aq[ks] = *(const bf16x8*)(q + (bT + q0 + lr) * H_ + ks * 32 + lk);

    f32x4 oacc[4] = {};
    float mrow[4], lrow[4];
    #pragma unroll
    for (int i = 0; i < 4; ++i) { mrow[i] = -1e30f; lrow[i] = 0.f; }

    const int jmax = (q0 + 15) >> 6;

    for (int jc = 0; jc <= jmax; ++jc) {
        const int kv0 = jc << 6;

        // S = Q K^T : B-frags direct from k (row-major), contiguous 16B
        f32x4 sacc[4] = {};
        #pragma unroll
        for (int jf = 0; jf < 4; ++jf)
            #pragma unroll
            for (int ks = 0; ks < 2; ++ks) {
                bf16x8 bk = *(const bf16x8*)(k + (bT + kv0 + jf * 16 + lr) * H_ + ks * 32 + lk);
                sacc[jf] = __builtin_amdgcn_mfma_f32_16x16x32_bf16(aq[ks], bk, sacc[jf], 0, 0, 0);
            }

        // scale + causal mask (skip mask on fully-valid chunks)
        const bool full = (kv0 + 63 <= q0);
        float s[4][4];
        #pragma unroll
        for (int jf = 0; jf < 4; ++jf) {
            int col = kv0 + jf * 16 + lr;
            #pragma unroll
            for (int i = 0; i < 4; ++i) {
                int row = q0 + g * 4 + i;
                float val = sacc[jf][i] * 0.03125f;
                s[jf][i] = (full || col <= row) ? val : -1e30f;
            }
        }

        // online softmax (row r lives across 16 lanes; reduce via shfl_xor 1,2,4,8)
        float pnew[4][4];
        #pragma unroll
        for (int i = 0; i < 4; ++i) {
            float mx = fmaxf(fmaxf(s[0][i], s[1][i]), fmaxf(s[2][i], s[3][i]));
            mx = fmaxf(mx, __shfl_xor(mx, 1));
            mx = fmaxf(mx, __shfl_xor(mx, 2));
            mx = fmaxf(mx, __shfl_xor(mx, 4));
            mx = fmaxf(mx, __shfl_xor(mx, 8));
            float mnew = fmaxf(mrow[i], mx);
            float corr = __expf(mrow[i] - mnew);
            float rs = 0.f;
            #pragma unroll
            for (int jf = 0; jf < 4; ++jf) {
                float p = __expf(s[jf][i] - mnew);
                pnew[jf][i] = p;
                rs += p;
            }
            rs += __shfl_xor(rs, 1);
            rs += __shfl_xor(rs, 2);
            rs += __shfl_xor(rs, 4);
            rs += __shfl_xor(rs, 8);
            lrow[i] = lrow[i] * corr + rs;
            mrow[i] = mnew;
            #pragma unroll
            for (int jf = 0; jf < 4; ++jf) oacc[jf][i] *= corr;
        }

        // P -> LDS (C/D layout -> A layout), then PV
        __syncthreads();
        #pragma unroll
        for (int jf = 0; jf < 4; ++jf)
            #pragma unroll
            for (int i = 0; i < 4; ++i)
                ps[(g * 4 + i) * 72 + jf * 16 + lr] = f2bf(pnew[jf][i]);
        __syncthreads();

        #pragma unroll
        for (int ks2 = 0; ks2 < 2; ++ks2) {
            bf16x8 ap = *(const bf16x8*)(ps + lr * 72 + ks2 * 32 + lk);
            #pragma unroll
            for (int jf = 0; jf < 4; ++jf) {
                bf16x8 bv = *(const bf16x8*)(vT + ((size_t)b * H_ + jf * 16 + lr) * T_ + kv0 + ks2 * 32 + lk);
                oacc[jf] = __builtin_amdgcn_mfma_f32_16x16x32_bf16(ap, bv, oacc[jf], 0, 0, 0);
            }
        }
    }

    // epilogue
    #pragma unroll
    for (int jf = 0; jf < 4; ++jf)
        #pragma unroll
        for (int i = 0; i < 4; ++i) {
            int row = q0 + g * 4 + i;
            out[(bT + row) * H_ + jf * 16 + lr] = oacc[jf][i] / lrow[i];
        }
}

extern "C" void kernel_launch(void* const* d_in, const int* in_sizes, int n_in,
                              void* d_out, int out_size, void* d_ws, size_t ws_size,
                              hipStream_t stream) {
    const float* x  = (const float*)d_in[0];
    const float* wq = (const float*)d_in[1];
    const float* wk = (const float*)d_in[2];
    const float* wv = (const float*)d_in[3];

    u16* qws  = (u16*)d_ws;                         // 1 MB
    u16* kws  = qws + (size_t)B_ * T_ * H_;         // 1 MB
    u16* vTws = kws + (size_t)B_ * T_ * H_;         // 1 MB
    u16* wcat = vTws + (size_t)B_ * T_ * H_;        // 384 KB

    wcvt<<<192, 256, 0, stream>>>(wq, wk, wv, wcat);
    qkv<<<256, 256, 0, stream>>>(x, wcat, qws, kws, vTws);
    attn<<<512, 64, 0, stream>>>(qws, kws, vTws, (float*)d_out);
}

// Round 4
// 78.415 us; speedup vs baseline: 2.1671x; 1.1485x over previous
//
#include <hip/hip_runtime.h>
#include <hip/hip_bf16.h>

typedef unsigned short u16;
typedef __attribute__((ext_vector_type(8))) __bf16 bf16x8;
typedef __attribute__((ext_vector_type(4))) float f32x4;

#define B_ 4
#define T_ 2048
#define C_ 1024
#define H_ 64
#define NSEG 4

__device__ __forceinline__ u16 f2bf(float f) {
    union { __hip_bfloat16 h; u16 u; } cv;
    cv.h = __float2bfloat16(f);
    return cv.u;
}

// ---------------- Kernel 0: W fp32 -> bf16 (once) ----------------
// wcat[192][1024]: rows 0-63 Wq, 64-127 Wk, 128-191 Wv
__global__ __launch_bounds__(256) void wcvt(
    const float* __restrict__ wq, const float* __restrict__ wk,
    const float* __restrict__ wv, u16* __restrict__ wcat)
{
    int e = (blockIdx.x * 256 + threadIdx.x) * 4;
    int row = e >> 10, col = e & 1023;
    const float* src = (row < 64) ? (wq + (size_t)row * C_)
                     : (row < 128) ? (wk + (size_t)(row - 64) * C_)
                                   : (wv + (size_t)(row - 128) * C_);
    float4 f = *(const float4*)(src + col);
    u16 o[4] = { f2bf(f.x), f2bf(f.y), f2bf(f.z), f2bf(f.w) };
    *(uint2*)(wcat + e) = *(uint2*)o;
}

// ---------------- Kernel 1: QKV projection, K-split x4 ----------------
// Block = one 16-row M-tile, 4 waves; wave w owns K range [w*256,(w+1)*256),
// all 192 N cols. Partials combined via LDS, wave 0 writes epilogue.
__global__ __launch_bounds__(256) void qkv(
    const float* __restrict__ x, const u16* __restrict__ wcat,
    u16* __restrict__ q, u16* __restrict__ k, u16* __restrict__ vT)
{
    __shared__ float red[3][16][196];   // pitch 196: 2-way-max bank alias (free)

    const int tid  = threadIdx.x;
    const int lane = tid & 63;
    const int w    = tid >> 6;
    const int m0   = blockIdx.x * 16;

    const int lr = lane & 15;
    const int g  = lane >> 4;

    const float* xrow = x + (size_t)(m0 + lr) * C_ + w * 256 + g * 8;
    const u16*   wb   = wcat + (size_t)lr * C_ + w * 256 + g * 8;

    f32x4 acc[12] = {};

    #pragma unroll
    for (int it = 0; it < 8; ++it) {
        const int k0 = it * 32;
        float4 f0 = *(const float4*)(xrow + k0);
        float4 f1 = *(const float4*)(xrow + k0 + 4);
        union { u16 h[8]; bf16x8 v; } ua;
        ua.h[0] = f2bf(f0.x); ua.h[1] = f2bf(f0.y);
        ua.h[2] = f2bf(f0.z); ua.h[3] = f2bf(f0.w);
        ua.h[4] = f2bf(f1.x); ua.h[5] = f2bf(f1.y);
        ua.h[6] = f2bf(f1.z); ua.h[7] = f2bf(f1.w);
        #pragma unroll
        for (int j = 0; j < 12; ++j) {
            bf16x8 b = *(const bf16x8*)(wb + (size_t)j * 16 * C_ + k0);
            acc[j] = __builtin_amdgcn_mfma_f32_16x16x32_bf16(ua.v, b, acc[j], 0, 0, 0);
        }
    }

    if (w > 0) {
        #pragma unroll
        for (int j = 0; j < 12; ++j)
            #pragma unroll
            for (int i = 0; i < 4; ++i)
                red[w - 1][g * 4 + i][j * 16 + lr] = acc[j][i];
    }
    __syncthreads();
    if (w != 0) return;

    #pragma unroll
    for (int j = 0; j < 12; ++j)
        #pragma unroll
        for (int i = 0; i < 4; ++i)
            acc[j][i] += red[0][g * 4 + i][j * 16 + lr]
                       + red[1][g * 4 + i][j * 16 + lr]
                       + red[2][g * 4 + i][j * 16 + lr];

    // epilogue: C/D layout col=lane&15, row=(lane>>4)*4+i
    #pragma unroll
    for (int j = 0; j < 12; ++j) {
        int n = j * 16 + lr;
        #pragma unroll
        for (int i = 0; i < 4; ++i) {
            int m = m0 + g * 4 + i;
            u16 val = f2bf(acc[j][i]);
            if (n < 64) {
                q[(size_t)m * H_ + n] = val;
            } else if (n < 128) {
                k[(size_t)m * H_ + (n - 64)] = val;
            } else {
                int b = m >> 11, t = m & 2047;
                vT[((size_t)b * H_ + (n - 128)) * T_ + t] = val;
            }
        }
    }
}

// ---------------- Kernel 2: causal flash attention, KV-split partials ----
// Block = (q-tile, segment); segment s handles chunks [s*L, min(nch,(s+1)*L)).
// Writes unnormalized o-partial + (m,l) per row.
__global__ __launch_bounds__(64) void attn_part(
    const u16* __restrict__ q, const u16* __restrict__ k,
    const u16* __restrict__ vT, float* __restrict__ opart,
    float* __restrict__ ml)
{
    __shared__ u16 ps[16 * 72];

    const int lane = threadIdx.x;
    const int bid  = blockIdx.x;
    const int seg  = bid & 3;
    const int tix  = bid >> 2;
    const int b    = tix & 3;
    const int qt   = 127 - (tix >> 2);
    const int q0   = qt * 16;
    const size_t bT = (size_t)b * T_;

    const int lr = lane & 15;
    const int g  = lane >> 4;
    const int lk = g * 8;

    const int nch = (qt >> 2) + 1;            // chunks of 64 in causal range
    const int L   = (nch + NSEG - 1) >> 2;
    const int c0  = seg * L;
    const int c1  = min(nch, c0 + L);

    if (c0 >= c1) {                            // empty segment: mark and leave
        if (lr == 0)
            #pragma unroll
            for (int i = 0; i < 4; ++i) {
                ml[(size_t)bid * 32 + (g * 4 + i) * 2]     = -1e30f;
                ml[(size_t)bid * 32 + (g * 4 + i) * 2 + 1] = 0.f;
            }
        return;
    }

    bf16x8 aq[2];
    #pragma unroll
    for (int ks = 0; ks < 2; ++ks)
        aq[ks] = *(const bf16x8*)(q + (bT + q0 + lr) * H_ + ks * 32 + lk);

    f32x4 oacc[4] = {};
    float mrow[4], lrow[4];
    #pragma unroll
    for (int i = 0; i < 4; ++i) { mrow[i] = -1e30f; lrow[i] = 0.f; }

    for (int jc = c0; jc < c1; ++jc) {
        const int kv0 = jc << 6;

        // S = Q K^T : B-frags direct from k (row-major), contiguous 16B
        f32x4 sacc[4] = {};
        #pragma unroll
        for (int jf = 0; jf < 4; ++jf)
            #pragma unroll
            for (int ks = 0; ks < 2; ++ks) {
                bf16x8 bk = *(const bf16x8*)(k + (bT + kv0 + jf * 16 + lr) * H_ + ks * 32 + lk);
                sacc[jf] = __builtin_amdgcn_mfma_f32_16x16x32_bf16(aq[ks], bk, sacc[jf], 0, 0, 0);
            }

        const bool full = (kv0 + 63 <= q0);
        float s[4][4];
        #pragma unroll
        for (int jf = 0; jf < 4; ++jf) {
            int col = kv0 + jf * 16 + lr;
            #pragma unroll
            for (int i = 0; i < 4; ++i) {
                int row = q0 + g * 4 + i;
                float val = sacc[jf][i] * 0.03125f;
                s[jf][i] = (full || col <= row) ? val : -1e30f;
            }
        }

        float pnew[4][4];
        #pragma unroll
        for (int i = 0; i < 4; ++i) {
            float mx = fmaxf(fmaxf(s[0][i], s[1][i]), fmaxf(s[2][i], s[3][i]));
            mx = fmaxf(mx, __shfl_xor(mx, 1));
            mx = fmaxf(mx, __shfl_xor(mx, 2));
            mx = fmaxf(mx, __shfl_xor(mx, 4));
            mx = fmaxf(mx, __shfl_xor(mx, 8));
            float mnew = fmaxf(mrow[i], mx);
            float corr = __expf(mrow[i] - mnew);
            float rs = 0.f;
            #pragma unroll
            for (int jf = 0; jf < 4; ++jf) {
                float p = __expf(s[jf][i] - mnew);
                pnew[jf][i] = p;
                rs += p;
            }
            rs += __shfl_xor(rs, 1);
            rs += __shfl_xor(rs, 2);
            rs += __shfl_xor(rs, 4);
            rs += __shfl_xor(rs, 8);
            lrow[i] = lrow[i] * corr + rs;
            mrow[i] = mnew;
            #pragma unroll
            for (int jf = 0; jf < 4; ++jf) oacc[jf][i] *= corr;
        }

        __syncthreads();
        #pragma unroll
        for (int jf = 0; jf < 4; ++jf)
            #pragma unroll
            for (int i = 0; i < 4; ++i)
                ps[(g * 4 + i) * 72 + jf * 16 + lr] = f2bf(pnew[jf][i]);
        __syncthreads();

        #pragma unroll
        for (int ks2 = 0; ks2 < 2; ++ks2) {
            bf16x8 ap = *(const bf16x8*)(ps + lr * 72 + ks2 * 32 + lk);
            #pragma unroll
            for (int jf = 0; jf < 4; ++jf) {
                bf16x8 bv = *(const bf16x8*)(vT + ((size_t)b * H_ + jf * 16 + lr) * T_ + kv0 + ks2 * 32 + lk);
                oacc[jf] = __builtin_amdgcn_mfma_f32_16x16x32_bf16(ap, bv, oacc[jf], 0, 0, 0);
            }
        }
    }

    // write partials (unnormalized)
    #pragma unroll
    for (int jf = 0; jf < 4; ++jf)
        #pragma unroll
        for (int i = 0; i < 4; ++i)
            opart[(size_t)bid * 1024 + (g * 4 + i) * 64 + jf * 16 + lr] = oacc[jf][i];
    if (lr == 0)
        #pragma unroll
        for (int i = 0; i < 4; ++i) {
            ml[(size_t)bid * 32 + (g * 4 + i) * 2]     = mrow[i];
            ml[(size_t)bid * 32 + (g * 4 + i) * 2 + 1] = lrow[i];
        }
}

// ---------------- Kernel 3: merge segments ----------------
__global__ __launch_bounds__(64) void attn_reduce(
    const float* __restrict__ opart, const float* __restrict__ ml,
    float* __restrict__ out)
{
    const int t    = blockIdx.x;
    const int lane = threadIdx.x;
    const int b    = t & 3;
    const int qt   = 127 - (t >> 2);

    for (int row = 0; row < 16; ++row) {
        float m[NSEG], l[NSEG];
        #pragma unroll
        for (int s = 0; s < NSEG; ++s) {
            m[s] = ml[(size_t)(t * 4 + s) * 32 + row * 2];
            l[s] = ml[(size_t)(t * 4 + s) * 32 + row * 2 + 1];
        }
        float M = fmaxf(fmaxf(m[0], m[1]), fmaxf(m[2], m[3]));
        float acc = 0.f, Lsum = 0.f;
        #pragma unroll
        for (int s = 0; s < NSEG; ++s) {
            float wgt = __expf(m[s] - M);
            Lsum += l[s] * wgt;
            acc  += wgt * opart[(size_t)(t * 4 + s) * 1024 + row * 64 + lane];
        }
        out[((size_t)b * T_ + qt * 16 + row) * H_ + lane] = acc / Lsum;
    }
}

extern "C" void kernel_launch(void* const* d_in, const int* in_sizes, int n_in,
                              void* d_out, int out_size, void* d_ws, size_t ws_size,
                              hipStream_t stream) {
    const float* x  = (const float*)d_in[0];
    const float* wq = (const float*)d_in[1];
    const float* wk = (const float*)d_in[2];
    const float* wv = (const float*)d_in[3];

    u16* qws  = (u16*)d_ws;                          // 1 MB
    u16* kws  = qws + (size_t)B_ * T_ * H_;          // 1 MB
    u16* vTws = kws + (size_t)B_ * T_ * H_;          // 1 MB
    u16* wcat = vTws + (size_t)B_ * T_ * H_;         // 384 KB
    float* fbase = (float*)(wcat + 192 * C_);        // 16B-aligned
    float* opart = fbase;                            // 2048*1024 f32 = 8.4 MB
    float* mlbuf = fbase + (size_t)2048 * 1024;      // 2048*32 f32 = 256 KB

    wcvt<<<192, 256, 0, stream>>>(wq, wk, wv, wcat);
    qkv<<<512, 256, 0, stream>>>(x, wcat, qws, kws, vTws);
    attn_part<<<2048, 64, 0, stream>>>(qws, kws, vTws, opart, mlbuf);
    attn_reduce<<<512, 64, 0, stream>>>(opart, mlbuf, (float*)d_out);
}

// Round 5
// 65.566 us; speedup vs baseline: 2.5917x; 1.1960x over previous
//
#include <hip/hip_runtime.h>
#include <hip/hip_bf16.h>

typedef unsigned short u16;
typedef __attribute__((ext_vector_type(8))) __bf16 bf16x8;
typedef __attribute__((ext_vector_type(4))) float f32x4;

#define B_ 4
#define T_ 2048
#define C_ 1024
#define H_ 64
#define NSEG 8

__device__ __forceinline__ u16 f2bf(float f) {
    union { __hip_bfloat16 h; u16 u; } cv;
    cv.h = __float2bfloat16(f);
    return cv.u;
}

// ---------------- Kernel 0: W fp32 -> bf16 (once) ----------------
__global__ __launch_bounds__(256) void wcvt(
    const float* __restrict__ wq, const float* __restrict__ wk,
    const float* __restrict__ wv, u16* __restrict__ wcat)
{
    int e = (blockIdx.x * 256 + threadIdx.x) * 4;
    int row = e >> 10, col = e & 1023;
    const float* src = (row < 64) ? (wq + (size_t)row * C_)
                     : (row < 128) ? (wk + (size_t)(row - 64) * C_)
                                   : (wv + (size_t)(row - 128) * C_);
    float4 f = *(const float4*)(src + col);
    u16 o[4] = { f2bf(f.x), f2bf(f.y), f2bf(f.z), f2bf(f.w) };
    *(uint2*)(wcat + e) = *(uint2*)o;
}

// ---------------- Kernel 1: QKV projection, K-split x4, upfront loads ----
__global__ __launch_bounds__(256) void qkv(
    const float* __restrict__ x, const u16* __restrict__ wcat,
    u16* __restrict__ q, u16* __restrict__ k, u16* __restrict__ vT)
{
    __shared__ float red[3][16][196];

    const int tid  = threadIdx.x;
    const int lane = tid & 63;
    const int w    = tid >> 6;
    const int m0   = blockIdx.x * 16;

    const int lr = lane & 15;
    const int g  = lane >> 4;

    const float* xrow = x + (size_t)(m0 + lr) * C_ + w * 256 + g * 8;
    const u16*   wb   = wcat + (size_t)lr * C_ + w * 256 + g * 8;

    // issue ALL x loads for this wave's K-slice upfront (16 independent float4s)
    float4 xf[16];
    #pragma unroll
    for (int it = 0; it < 8; ++it) {
        xf[2 * it]     = *(const float4*)(xrow + it * 32);
        xf[2 * it + 1] = *(const float4*)(xrow + it * 32 + 4);
    }

    f32x4 acc[12] = {};

    #pragma unroll
    for (int it = 0; it < 8; ++it) {
        float4 f0 = xf[2 * it], f1 = xf[2 * it + 1];
        union { u16 h[8]; bf16x8 v; } ua;
        ua.h[0] = f2bf(f0.x); ua.h[1] = f2bf(f0.y);
        ua.h[2] = f2bf(f0.z); ua.h[3] = f2bf(f0.w);
        ua.h[4] = f2bf(f1.x); ua.h[5] = f2bf(f1.y);
        ua.h[6] = f2bf(f1.z); ua.h[7] = f2bf(f1.w);
        #pragma unroll
        for (int j = 0; j < 12; ++j) {
            bf16x8 b = *(const bf16x8*)(wb + (size_t)j * 16 * C_ + it * 32);
            acc[j] = __builtin_amdgcn_mfma_f32_16x16x32_bf16(ua.v, b, acc[j], 0, 0, 0);
        }
    }

    if (w > 0) {
        #pragma unroll
        for (int j = 0; j < 12; ++j)
            #pragma unroll
            for (int i = 0; i < 4; ++i)
                red[w - 1][g * 4 + i][j * 16 + lr] = acc[j][i];
    }
    __syncthreads();
    if (w != 0) return;

    #pragma unroll
    for (int j = 0; j < 12; ++j)
        #pragma unroll
        for (int i = 0; i < 4; ++i)
            acc[j][i] += red[0][g * 4 + i][j * 16 + lr]
                       + red[1][g * 4 + i][j * 16 + lr]
                       + red[2][g * 4 + i][j * 16 + lr];

    #pragma unroll
    for (int j = 0; j < 12; ++j) {
        int n = j * 16 + lr;
        #pragma unroll
        for (int i = 0; i < 4; ++i) {
            int m = m0 + g * 4 + i;
            u16 val = f2bf(acc[j][i]);
            if (n < 64) {
                q[(size_t)m * H_ + n] = val;
            } else if (n < 128) {
                k[(size_t)m * H_ + (n - 64)] = val;
            } else {
                int b = m >> 11, t = m & 2047;
                vT[((size_t)b * H_ + (n - 128)) * T_ + t] = val;
            }
        }
    }
}

// ---------------- Kernel 2: causal flash attention, KV-split x8 ----------
__global__ __launch_bounds__(64) void attn_part(
    const u16* __restrict__ q, const u16* __restrict__ k,
    const u16* __restrict__ vT, float* __restrict__ opart,
    float* __restrict__ ml)
{
    __shared__ u16 ps[16 * 72];

    const int lane = threadIdx.x;
    const int bid  = blockIdx.x;
    const int seg  = bid & (NSEG - 1);
    const int tix  = bid >> 3;
    const int b    = tix & 3;
    const int qt   = 127 - (tix >> 2);
    const int q0   = qt * 16;
    const size_t bT = (size_t)b * T_;

    const int lr = lane & 15;
    const int g  = lane >> 4;
    const int lk = g * 8;

    const int nch = (qt >> 2) + 1;
    const int L   = (nch + NSEG - 1) >> 3;
    const int c0  = seg * L;
    const int c1  = min(nch, c0 + L);

    if (c0 >= c1) {
        if (lr == 0)
            #pragma unroll
            for (int i = 0; i < 4; ++i) {
                ml[(size_t)bid * 32 + (g * 4 + i) * 2]     = -1e30f;
                ml[(size_t)bid * 32 + (g * 4 + i) * 2 + 1] = 0.f;
            }
        return;
    }

    bf16x8 aq[2];
    #pragma unroll
    for (int ks = 0; ks < 2; ++ks)
        aq[ks] = *(const bf16x8*)(q + (bT + q0 + lr) * H_ + ks * 32 + lk);

    f32x4 oacc[4] = {};
    float mrow[4], lrow[4];
    #pragma unroll
    for (int i = 0; i < 4; ++i) { mrow[i] = -1e30f; lrow[i] = 0.f; }

    for (int jc = c0; jc < c1; ++jc) {
        const int kv0 = jc << 6;

        // batch-issue the 8 K-fragment loads, then QK^T
        bf16x8 bk[8];
        #pragma unroll
        for (int jf = 0; jf < 4; ++jf)
            #pragma unroll
            for (int ks = 0; ks < 2; ++ks)
                bk[jf * 2 + ks] = *(const bf16x8*)(k + (bT + kv0 + jf * 16 + lr) * H_ + ks * 32 + lk);

        f32x4 sacc[4] = {};
        #pragma unroll
        for (int jf = 0; jf < 4; ++jf)
            #pragma unroll
            for (int ks = 0; ks < 2; ++ks)
                sacc[jf] = __builtin_amdgcn_mfma_f32_16x16x32_bf16(aq[ks], bk[jf * 2 + ks], sacc[jf], 0, 0, 0);

        const bool full = (kv0 + 63 <= q0);
        float s[4][4];
        #pragma unroll
        for (int jf = 0; jf < 4; ++jf) {
            int col = kv0 + jf * 16 + lr;
            #pragma unroll
            for (int i = 0; i < 4; ++i) {
                int row = q0 + g * 4 + i;
                float val = sacc[jf][i] * 0.03125f;
                s[jf][i] = (full || col <= row) ? val : -1e30f;
            }
        }

        float pnew[4][4];
        #pragma unroll
        for (int i = 0; i < 4; ++i) {
            float mx = fmaxf(fmaxf(s[0][i], s[1][i]), fmaxf(s[2][i], s[3][i]));
            mx = fmaxf(mx, __shfl_xor(mx, 1));
            mx = fmaxf(mx, __shfl_xor(mx, 2));
            mx = fmaxf(mx, __shfl_xor(mx, 4));
            mx = fmaxf(mx, __shfl_xor(mx, 8));
            float mnew = fmaxf(mrow[i], mx);
            float corr = __expf(mrow[i] - mnew);
            float rs = 0.f;
            #pragma unroll
            for (int jf = 0; jf < 4; ++jf) {
                float p = __expf(s[jf][i] - mnew);
                pnew[jf][i] = p;
                rs += p;
            }
            rs += __shfl_xor(rs, 1);
            rs += __shfl_xor(rs, 2);
            rs += __shfl_xor(rs, 4);
            rs += __shfl_xor(rs, 8);
            lrow[i] = lrow[i] * corr + rs;
            mrow[i] = mnew;
            #pragma unroll
            for (int jf = 0; jf < 4; ++jf) oacc[jf][i] *= corr;
        }

        // P -> LDS; V loads issue while the LDS round-trip drains
        __syncthreads();
        #pragma unroll
        for (int jf = 0; jf < 4; ++jf)
            #pragma unroll
            for (int i = 0; i < 4; ++i)
                ps[(g * 4 + i) * 72 + jf * 16 + lr] = f2bf(pnew[jf][i]);

        bf16x8 bv[8];
        #pragma unroll
        for (int jf = 0; jf < 4; ++jf)
            #pragma unroll
            for (int ks = 0; ks < 2; ++ks)
                bv[jf * 2 + ks] = *(const bf16x8*)(vT + ((size_t)b * H_ + jf * 16 + lr) * T_ + kv0 + ks * 32 + lk);

        __syncthreads();

        #pragma unroll
        for (int ks2 = 0; ks2 < 2; ++ks2) {
            bf16x8 ap = *(const bf16x8*)(ps + lr * 72 + ks2 * 32 + lk);
            #pragma unroll
            for (int jf = 0; jf < 4; ++jf)
                oacc[jf] = __builtin_amdgcn_mfma_f32_16x16x32_bf16(ap, bv[jf * 2 + ks2], oacc[jf], 0, 0, 0);
        }
    }

    #pragma unroll
    for (int jf = 0; jf < 4; ++jf)
        #pragma unroll
        for (int i = 0; i < 4; ++i)
            opart[(size_t)bid * 1024 + (g * 4 + i) * 64 + jf * 16 + lr] = oacc[jf][i];
    if (lr == 0)
        #pragma unroll
        for (int i = 0; i < 4; ++i) {
            ml[(size_t)bid * 32 + (g * 4 + i) * 2]     = mrow[i];
            ml[(size_t)bid * 32 + (g * 4 + i) * 2 + 1] = lrow[i];
        }
}

// ---------------- Kernel 3: merge segments (vectorized) ----------------
__global__ __launch_bounds__(256) void attn_reduce(
    const float* __restrict__ opart, const float* __restrict__ ml,
    float* __restrict__ out)
{
    const int t   = blockIdx.x;
    const int row = threadIdx.x >> 4;
    const int p   = threadIdx.x & 15;
    const int b   = t & 3;
    const int qt  = 127 - (t >> 2);

    float m[NSEG], l[NSEG];
    #pragma unroll
    for (int s = 0; s < NSEG; ++s) {
        m[s] = ml[(size_t)(t * NSEG + s) * 32 + row * 2];
        l[s] = ml[(size_t)(t * NSEG + s) * 32 + row * 2 + 1];
    }
    float M = m[0];
    #pragma unroll
    for (int s = 1; s < NSEG; ++s) M = fmaxf(M, m[s]);

    float a0 = 0.f, a1 = 0.f, a2 = 0.f, a3 = 0.f, Lsum = 0.f;
    #pragma unroll
    for (int s = 0; s < NSEG; ++s) {
        float wgt = __expf(m[s] - M);
        Lsum += l[s] * wgt;
        float4 o = *(const float4*)(opart + (size_t)(t * NSEG + s) * 1024 + row * 64 + p * 4);
        a0 += wgt * o.x; a1 += wgt * o.y; a2 += wgt * o.z; a3 += wgt * o.w;
    }
    float inv = 1.f / Lsum;
    float4 r; r.x = a0 * inv; r.y = a1 * inv; r.z = a2 * inv; r.w = a3 * inv;
    *(float4*)(out + ((size_t)b * T_ + qt * 16 + row) * H_ + p * 4) = r;
}

extern "C" void kernel_launch(void* const* d_in, const int* in_sizes, int n_in,
                              void* d_out, int out_size, void* d_ws, size_t ws_size,
                              hipStream_t stream) {
    const float* x  = (const float*)d_in[0];
    const float* wq = (const float*)d_in[1];
    const float* wk = (const float*)d_in[2];
    const float* wv = (const float*)d_in[3];

    u16* qws  = (u16*)d_ws;                          // 1 MB
    u16* kws  = qws + (size_t)B_ * T_ * H_;          // 1 MB
    u16* vTws = kws + (size_t)B_ * T_ * H_;          // 1 MB
    u16* wcat = vTws + (size_t)B_ * T_ * H_;         // 384 KB
    float* fbase = (float*)(wcat + 192 * C_);
    float* opart = fbase;                            // 4096*1024 f32 = 16.8 MB
    float* mlbuf = fbase + (size_t)4096 * 1024;      // 4096*32 f32 = 512 KB

    wcvt<<<192, 256, 0, stream>>>(wq, wk, wv, wcat);
    qkv<<<512, 256, 0, stream>>>(x, wcat, qws, kws, vTws);
    attn_part<<<4096, 64, 0, stream>>>(qws, kws, vTws, opart, mlbuf);
    attn_reduce<<<512, 256, 0, stream>>>(opart, mlbuf, (float*)d_out);
}